// Round 3
// baseline (438.081 us; speedup 1.0000x reference)
//
#include <hip/hip_runtime.h>

#define T_IN   512
#define T_OUT  128
#define BATCH  65536

typedef float v2f __attribute__((ext_vector_type(2)));

__device__ __forceinline__ float exp2_fast(float v) { return __builtin_amdgcn_exp2f(v); }
__device__ __forceinline__ float rcp_fast(float v)  { return __builtin_amdgcn_rcpf(v); }

// DPP cross-lane mov (VALU pipe, no LDS). CTRL is a compile-time dpp_ctrl.
template<int CTRL>
__device__ __forceinline__ float dppf(float v) {
    return __int_as_float(__builtin_amdgcn_mov_dpp(__float_as_int(v), CTRL, 0xF, 0xF, false));
}
#define QP_XOR1 0xB1   // quad_perm [1,0,3,2]  : lane ^= 1
#define QP_XOR2 0x4E   // quad_perm [2,3,0,1]  : lane ^= 2
#define QP_XOR3 0x1B   // quad_perm [3,2,1,0]  : lane ^= 3
#define HALF_MIRROR 0x141  // row_half_mirror   : lane ^= 7 (within 8-lane halves)

// 8 lanes per batch element; lane owns unit u = tid&7 (8-lane-aligned groups).
// h allgather is 7 DPP movs into XOR order: hw[d] = h[u^d]. Weights are loaded
// once per phase in matching XOR order, pre-scaled by the exp2 constants:
//   r,z: sigmoid(s) = rcp(1 + exp2(-log2e*s));  n: tanh(s) = 1-2*rcp(1+exp2(2log2e*s))
__global__ __launch_bounds__(256, 8) void gru_seq2seq(
    const float* __restrict__ x,
    const float* __restrict__ eWih, const float* __restrict__ eWhh,
    const float* __restrict__ eBih, const float* __restrict__ eBhh,
    const float* __restrict__ dWih, const float* __restrict__ dWhh,
    const float* __restrict__ dBih, const float* __restrict__ dBhh,
    const float* __restrict__ fcW,  const float* __restrict__ fcB,
    float* __restrict__ out)
{
    const int tid = threadIdx.x;
    const int u   = tid & 7;                       // owned hidden unit
    const int e   = (int)blockIdx.x * 32 + (tid >> 3);

    const float CR = -1.44269504088896340736f;     // -log2(e)
    const float CN =  2.88539008177792681472f;     //  2*log2(e)

    v2f wr[4], wz[4], wn[4];                       // W_hh rows, XOR-ordered cols
    v2f brv, bzv, bnv;                             // bias seeds {b,0}
    float wir, wiz, win, binS;

    auto load_w = [&](const float* Wih, const float* Whh,
                      const float* Bih, const float* Bhh) {
        #pragma unroll
        for (int p = 0; p < 4; ++p) {
            const int c0 = u ^ (2*p), c1 = u ^ (2*p + 1);
            wr[p] = v2f{ Whh[u*8      + c0] * CR, Whh[u*8      + c1] * CR };
            wz[p] = v2f{ Whh[(u+8)*8  + c0] * CR, Whh[(u+8)*8  + c1] * CR };
            wn[p] = v2f{ Whh[(u+16)*8 + c0] * CN, Whh[(u+16)*8 + c1] * CN };
        }
        wir = Wih[u]    * CR;  wiz = Wih[u+8] * CR;  win = Wih[u+16] * CN;
        brv = v2f{ (Bih[u]   + Bhh[u])   * CR, 0.f };
        bzv = v2f{ (Bih[u+8] + Bhh[u+8]) * CR, 0.f };
        bnv = v2f{ Bhh[u+16] * CN,             0.f };
        binS = Bih[u+16] * CN;
    };

    load_w(eWih, eWhh, eBih, eBhh);

    float h = 0.0f;
    v2f h01 = {0.f,0.f}, h23 = {0.f,0.f}, h45 = {0.f,0.f}, h67 = {0.f,0.f};

    auto cell = [&](float xin) {
        v2f ar = __builtin_elementwise_fma(wr[0], h01, brv);
        v2f az = __builtin_elementwise_fma(wz[0], h01, bzv);
        v2f an = __builtin_elementwise_fma(wn[0], h01, bnv);
        ar = __builtin_elementwise_fma(wr[1], h23, ar);
        az = __builtin_elementwise_fma(wz[1], h23, az);
        an = __builtin_elementwise_fma(wn[1], h23, an);
        ar = __builtin_elementwise_fma(wr[2], h45, ar);
        az = __builtin_elementwise_fma(wz[2], h45, az);
        an = __builtin_elementwise_fma(wn[2], h45, an);
        ar = __builtin_elementwise_fma(wr[3], h67, ar);
        az = __builtin_elementwise_fma(wz[3], h67, az);
        an = __builtin_elementwise_fma(wn[3], h67, an);

        const float sr = fmaf(xin, wir, ar.x + ar.y);
        const float sz = fmaf(xin, wiz, az.x + az.y);
        const float hn = an.x + an.y;

        const float er = exp2_fast(sr);
        const float ez = exp2_fast(sz);
        const float dr = 1.0f + er;
        const float dz = 1.0f + ez;
        const float rp = rcp_fast(dr * dz);          // shared reciprocal
        const float r  = dz * rp;
        const float z  = dr * rp;

        float pre = fmaf(xin, win, binS);
        pre = fmaf(r, hn, pre);
        const float en = exp2_fast(pre);
        const float rn = rcp_fast(1.0f + en);
        const float n  = fmaf(-2.0f, rn, 1.0f);      // tanh

        h = fmaf(z, h - n, n);                       // (1-z)*n + z*h

        // allgather into XOR order: hw[d] = h[u^d]  (7 DPP movs, no LDS)
        h01.x = h;
        h01.y = dppf<QP_XOR1>(h);                    // u^1
        h23.x = dppf<QP_XOR2>(h);                    // u^2
        h23.y = dppf<QP_XOR1>(h23.x);                // u^3
        h67.y = dppf<HALF_MIRROR>(h);                // u^7
        h67.x = dppf<QP_XOR1>(h67.y);                // u^6
        h45.y = dppf<QP_XOR2>(h67.y);                // u^5
        h45.x = dppf<QP_XOR3>(h67.y);                // u^4
    };

    // ---------------- encoder: 512 steps, prefetch distance 2, tail peeled ----------------
    const float* xp = x + e;
    float x0 = xp[0];
    float x1 = xp[BATCH];
    xp += 2 * (size_t)BATCH;
    #pragma unroll 2
    for (int t = 0; t < T_IN - 2; ++t) {
        const float x2 = *xp; xp += BATCH;
        cell(x0);
        x0 = x1; x1 = x2;
    }
    cell(x0);      // t = 510
    cell(x1);      // t = 511; x1 == x[511] == decoder's first input

    // ---------------- decoder: 128 steps ----------------
    load_w(dWih, dWhh, dBih, dBhh);
    v2f fw[4];
    #pragma unroll
    for (int p = 0; p < 4; ++p)
        fw[p] = v2f{ fcW[u ^ (2*p)], fcW[u ^ (2*p + 1)] };
    const v2f fbv = v2f{ fcB[0], 0.f };

    float inp = x1;
    float* outp = out + e;
    #pragma unroll 1
    for (int t = 0; t < T_OUT; ++t) {
        cell(inp);
        v2f ay = __builtin_elementwise_fma(fw[0], h01, fbv);
        ay = __builtin_elementwise_fma(fw[1], h23, ay);
        ay = __builtin_elementwise_fma(fw[2], h45, ay);
        ay = __builtin_elementwise_fma(fw[3], h67, ay);
        const float y = ay.x + ay.y;
        if (u == 0) outp[t * BATCH] = y;
        inp = y;
    }
}

extern "C" void kernel_launch(void* const* d_in, const int* in_sizes, int n_in,
                              void* d_out, int out_size, void* d_ws, size_t ws_size,
                              hipStream_t stream) {
    const float* x    = (const float*)d_in[0];
    const float* eWih = (const float*)d_in[1];
    const float* eWhh = (const float*)d_in[2];
    const float* eBih = (const float*)d_in[3];
    const float* eBhh = (const float*)d_in[4];
    const float* dWih = (const float*)d_in[5];
    const float* dWhh = (const float*)d_in[6];
    const float* dBih = (const float*)d_in[7];
    const float* dBhh = (const float*)d_in[8];
    const float* fcW  = (const float*)d_in[9];
    const float* fcB  = (const float*)d_in[10];
    float* out = (float*)d_out;

    dim3 grid(BATCH / 32);   // 2048 blocks = 8192 waves = exactly 8 waves/SIMD
    dim3 block(256);
    gru_seq2seq<<<grid, block, 0, stream>>>(x, eWih, eWhh, eBih, eBhh,
                                            dWih, dWhh, dBih, dBhh,
                                            fcW, fcB, out);
}

// Round 4
// 430.255 us; speedup vs baseline: 1.0182x; 1.0182x over previous
//
#include <hip/hip_runtime.h>

#define T_IN   512
#define T_OUT  128
#define BATCH  65536

typedef float v2f __attribute__((ext_vector_type(2)));

__device__ __forceinline__ float exp2_fast(float v) { return __builtin_amdgcn_exp2f(v); }
__device__ __forceinline__ float rcp_fast(float v)  { return __builtin_amdgcn_rcpf(v); }

// Guaranteed packed fp32 FMA (2 lanes of fp32 per instr, VOP3P).
__device__ __forceinline__ v2f pk_fma(v2f a, v2f b, v2f c) {
    v2f d;
    asm("v_pk_fma_f32 %0, %1, %2, %3" : "=v"(d) : "v"(a), "v"(b), "v"(c));
    return d;
}

// DPP cross-lane mov (VALU pipe, no LDS). CTRL is a compile-time dpp_ctrl.
template<int CTRL>
__device__ __forceinline__ float dppf(float v) {
    return __int_as_float(__builtin_amdgcn_mov_dpp(__float_as_int(v), CTRL, 0xF, 0xF, false));
}
#define QP_XOR1 0xB1       // quad_perm [1,0,3,2]  : lane ^= 1
#define QP_XOR2 0x4E       // quad_perm [2,3,0,1]  : lane ^= 2
#define QP_XOR3 0x1B       // quad_perm [3,2,1,0]  : lane ^= 3
#define HALF_MIRROR 0x141  // row_half_mirror      : lane ^= 7 (within 8-lane halves)

// 8 lanes per unit-group; each THREAD carries TWO batch elements (e, e+32) to
// fill dependency/DPP-hazard bubbles. Weights shared in regs, XOR-ordered,
// pre-scaled: r,z: sigmoid(s)=rcp(1+exp2(-log2e*s)); n: tanh(s)=1-2*rcp(1+exp2(2log2e*s))
__global__ __launch_bounds__(256, 4) void gru_seq2seq(
    const float* __restrict__ x,
    const float* __restrict__ eWih, const float* __restrict__ eWhh,
    const float* __restrict__ eBih, const float* __restrict__ eBhh,
    const float* __restrict__ dWih, const float* __restrict__ dWhh,
    const float* __restrict__ dBih, const float* __restrict__ dBhh,
    const float* __restrict__ fcW,  const float* __restrict__ fcB,
    float* __restrict__ out)
{
    const int tid = threadIdx.x;
    const int u   = tid & 7;                        // owned hidden unit
    const int e0  = (int)blockIdx.x * 64 + (tid >> 3);
    const int e1  = e0 + 32;

    const float CR = -1.44269504088896340736f;      // -log2(e)
    const float CN =  2.88539008177792681472f;      //  2*log2(e)

    v2f wr[4], wz[4], wn[4];                        // W_hh rows, XOR-ordered cols (shared)
    v2f brv, bzv, bnv;                              // bias seeds {b,0}
    float wir, wiz, win, binS;

    auto load_w = [&](const float* Wih, const float* Whh,
                      const float* Bih, const float* Bhh) {
        #pragma unroll
        for (int p = 0; p < 4; ++p) {
            const int c0 = u ^ (2*p), c1 = u ^ (2*p + 1);
            wr[p] = v2f{ Whh[u*8      + c0] * CR, Whh[u*8      + c1] * CR };
            wz[p] = v2f{ Whh[(u+8)*8  + c0] * CR, Whh[(u+8)*8  + c1] * CR };
            wn[p] = v2f{ Whh[(u+16)*8 + c0] * CN, Whh[(u+16)*8 + c1] * CN };
        }
        wir = Wih[u]    * CR;  wiz = Wih[u+8] * CR;  win = Wih[u+16] * CN;
        brv = v2f{ (Bih[u]   + Bhh[u])   * CR, 0.f };
        bzv = v2f{ (Bih[u+8] + Bhh[u+8]) * CR, 0.f };
        bnv = v2f{ Bhh[u+16] * CN,             0.f };
        binS = Bih[u+16] * CN;
    };

    load_w(eWih, eWhh, eBih, eBhh);

    float h[2] = {0.f, 0.f};
    v2f h01[2] = {{0.f,0.f},{0.f,0.f}}, h23[2] = {{0.f,0.f},{0.f,0.f}};
    v2f h45[2] = {{0.f,0.f},{0.f,0.f}}, h67[2] = {{0.f,0.f},{0.f,0.f}};

    // One GRU cell for element slot i (i is a compile-time constant at each call site).
    auto cell = [&](int i, float xin) {
        v2f ar = pk_fma(wr[0], h01[i], brv);
        v2f az = pk_fma(wz[0], h01[i], bzv);
        v2f an = pk_fma(wn[0], h01[i], bnv);
        ar = pk_fma(wr[1], h23[i], ar);
        az = pk_fma(wz[1], h23[i], az);
        an = pk_fma(wn[1], h23[i], an);
        ar = pk_fma(wr[2], h45[i], ar);
        az = pk_fma(wz[2], h45[i], az);
        an = pk_fma(wn[2], h45[i], an);
        ar = pk_fma(wr[3], h67[i], ar);
        az = pk_fma(wz[3], h67[i], az);
        an = pk_fma(wn[3], h67[i], an);

        const float sr = fmaf(xin, wir, ar.x + ar.y);
        const float sz = fmaf(xin, wiz, az.x + az.y);
        const float hn = an.x + an.y;

        const float er = exp2_fast(sr);
        const float ez = exp2_fast(sz);
        const float dr = 1.0f + er;
        const float dz = 1.0f + ez;
        const float rp = rcp_fast(dr * dz);          // shared reciprocal
        const float r  = dz * rp;
        const float z  = dr * rp;

        float pre = fmaf(xin, win, binS);
        pre = fmaf(r, hn, pre);
        const float en = exp2_fast(pre);
        const float rn = rcp_fast(1.0f + en);
        const float n  = fmaf(-2.0f, rn, 1.0f);      // tanh

        h[i] = fmaf(z, h[i] - n, n);                 // (1-z)*n + z*h

        // allgather into XOR order: hw[d] = h[u^d]  (7 DPP movs, no LDS)
        const float hh = h[i];
        h01[i].x = hh;
        h01[i].y = dppf<QP_XOR1>(hh);                // u^1
        h23[i].x = dppf<QP_XOR2>(hh);                // u^2
        h23[i].y = dppf<QP_XOR1>(h23[i].x);          // u^3
        h67[i].y = dppf<HALF_MIRROR>(hh);            // u^7
        h67[i].x = dppf<QP_XOR1>(h67[i].y);          // u^6
        h45[i].y = dppf<QP_XOR2>(h67[i].y);          // u^5
        h45[i].x = dppf<QP_XOR3>(h67[i].y);          // u^4
    };

    // ---------------- encoder: 512 steps, prefetch distance 2, tail peeled ----------------
    const float* xp = x + e0;
    float xa0 = xp[0],     xb0 = xp[32];
    float xa1 = xp[BATCH], xb1 = xp[BATCH + 32];
    xp += 2 * (size_t)BATCH;
    #pragma unroll 2
    for (int t = 0; t < T_IN - 2; ++t) {
        const float xa2 = xp[0];
        const float xb2 = xp[32];
        xp += BATCH;
        cell(0, xa0);
        cell(1, xb0);
        xa0 = xa1; xa1 = xa2;
        xb0 = xb1; xb1 = xb2;
    }
    cell(0, xa0); cell(1, xb0);      // t = 510
    cell(0, xa1); cell(1, xb1);      // t = 511; xa1/xb1 == x[511] == decoder first input

    // ---------------- decoder: 128 steps ----------------
    load_w(dWih, dWhh, dBih, dBhh);
    v2f fw[4];
    #pragma unroll
    for (int p = 0; p < 4; ++p)
        fw[p] = v2f{ fcW[u ^ (2*p)], fcW[u ^ (2*p + 1)] };
    const v2f fbv = v2f{ fcB[0], 0.f };

    float inp0 = xa1, inp1 = xb1;
    float* outp = out + e0;
    #pragma unroll 1
    for (int t = 0; t < T_OUT; ++t) {
        cell(0, inp0);
        cell(1, inp1);
        v2f ay0 = pk_fma(fw[0], h01[0], fbv);
        v2f ay1 = pk_fma(fw[0], h01[1], fbv);
        ay0 = pk_fma(fw[1], h23[0], ay0);
        ay1 = pk_fma(fw[1], h23[1], ay1);
        ay0 = pk_fma(fw[2], h45[0], ay0);
        ay1 = pk_fma(fw[2], h45[1], ay1);
        ay0 = pk_fma(fw[3], h67[0], ay0);
        ay1 = pk_fma(fw[3], h67[1], ay1);
        const float y0 = ay0.x + ay0.y;
        const float y1 = ay1.x + ay1.y;
        if (u == 0) {
            outp[t * BATCH]      = y0;
            outp[t * BATCH + 32] = y1;
        }
        inp0 = y0;
        inp1 = y1;
    }
}

extern "C" void kernel_launch(void* const* d_in, const int* in_sizes, int n_in,
                              void* d_out, int out_size, void* d_ws, size_t ws_size,
                              hipStream_t stream) {
    const float* x    = (const float*)d_in[0];
    const float* eWih = (const float*)d_in[1];
    const float* eWhh = (const float*)d_in[2];
    const float* eBih = (const float*)d_in[3];
    const float* eBhh = (const float*)d_in[4];
    const float* dWih = (const float*)d_in[5];
    const float* dWhh = (const float*)d_in[6];
    const float* dBih = (const float*)d_in[7];
    const float* dBhh = (const float*)d_in[8];
    const float* fcW  = (const float*)d_in[9];
    const float* fcB  = (const float*)d_in[10];
    float* out = (float*)d_out;

    dim3 grid(BATCH / 64);   // 1024 blocks; 2 elements per thread -> 4 waves/SIMD
    dim3 block(256);
    gru_seq2seq<<<grid, block, 0, stream>>>(x, eWih, eWhh, eBih, eBhh,
                                            dWih, dWhh, dBih, dBhh,
                                            fcW, fcB, out);
}

// Round 5
// 382.525 us; speedup vs baseline: 1.1452x; 1.1248x over previous
//
#include <hip/hip_runtime.h>

#define T_IN   512
#define T_OUT  128
#define BATCH  65536

typedef float v2f __attribute__((ext_vector_type(2)));

__device__ __forceinline__ float exp2_fast(float v) { return __builtin_amdgcn_exp2f(v); }
__device__ __forceinline__ float rcp_fast(float v)  { return __builtin_amdgcn_rcpf(v); }

// Guaranteed packed fp32 FMA (VOP3P, 2×f32 per instr).
__device__ __forceinline__ v2f pk_fma(v2f a, v2f b, v2f c) {
    v2f d;
    asm("v_pk_fma_f32 %0, %1, %2, %3" : "=v"(d) : "v"(a), "v"(b), "v"(c));
    return d;
}

// DPP cross-lane mov (VALU pipe, no LDS).
template<int CTRL>
__device__ __forceinline__ float dppf(float v) {
    return __int_as_float(__builtin_amdgcn_mov_dpp(__float_as_int(v), CTRL, 0xF, 0xF, false));
}
#define QP_XOR1 0xB1       // quad_perm [1,0,3,2]  : lane ^= 1
#define QP_XOR2 0x4E       // quad_perm [2,3,0,1]  : lane ^= 2
#define QP_XOR3 0x1B       // quad_perm [3,2,1,0]  : lane ^= 3
#define HALF_MIRROR 0x141  // row_half_mirror      : lane ^= 7 (within 8-lane halves)

// 8 lanes per unit-group; each thread carries TWO batch elements (e, e+32),
// SLOT-PACKED: every pair {slot0,slot1} lives in one v2f and all regular
// arithmetic is v_pk_*. Weights duplicated {w,w}; state hp[d]={h0[u^d],h1[u^d]}
// in XOR order so the allgather is 14 DPP movs. Transcendentals merged:
// one rcp for 4 sigmoid denominators, one rcp for 2 tanh denominators.
// Pre-scaled: r,z: sigmoid(s)=rcp(1+exp2(-log2e*s)); n: tanh=1-2*rcp(1+exp2(2log2e*s))
__global__ __launch_bounds__(256, 4) void gru_seq2seq(
    const float* __restrict__ x,
    const float* __restrict__ eWih, const float* __restrict__ eWhh,
    const float* __restrict__ eBih, const float* __restrict__ eBhh,
    const float* __restrict__ dWih, const float* __restrict__ dWhh,
    const float* __restrict__ dBih, const float* __restrict__ dBhh,
    const float* __restrict__ fcW,  const float* __restrict__ fcB,
    float* __restrict__ out)
{
    const int tid = threadIdx.x;
    const int u   = tid & 7;                        // owned hidden unit
    const int e0  = (int)blockIdx.x * 64 + (tid >> 3);   // slot0; slot1 = e0+32

    const float CR = -1.44269504088896340736f;      // -log2(e)
    const float CN =  2.88539008177792681472f;      //  2*log2(e)

    v2f wr[8], wz[8], wn[8];                        // W_hh, XOR-ordered, dup'd
    v2f wirv, wizv, winv;                           // W_ih rows, dup'd
    v2f brv, bzv, bnv, binv;                        // bias seeds, dup'd

    auto dup = [](float v) { return v2f{v, v}; };

    auto load_w = [&](const float* Wih, const float* Whh,
                      const float* Bih, const float* Bhh) {
        #pragma unroll
        for (int d = 0; d < 8; ++d) {
            const int c = u ^ d;
            wr[d] = dup(Whh[u*8      + c] * CR);
            wz[d] = dup(Whh[(u+8)*8  + c] * CR);
            wn[d] = dup(Whh[(u+16)*8 + c] * CN);
        }
        wirv = dup(Wih[u]    * CR);
        wizv = dup(Wih[u+8]  * CR);
        winv = dup(Wih[u+16] * CN);
        brv  = dup((Bih[u]   + Bhh[u])   * CR);
        bzv  = dup((Bih[u+8] + Bhh[u+8]) * CR);
        bnv  = dup(Bhh[u+16] * CN);
        binv = dup(Bih[u+16] * CN);
    };

    load_w(eWih, eWhh, eBih, eBhh);

    const v2f C_NEG2 = {-2.f, -2.f};
    const v2f C_ONE  = { 1.f,  1.f};

    v2f hp[8];                                      // hp[d] = {h0[u^d], h1[u^d]}
    #pragma unroll
    for (int d = 0; d < 8; ++d) hp[d] = v2f{0.f, 0.f};

    // One GRU step for BOTH slots. xp = {x_slot0, x_slot1}.
    auto cell2 = [&](v2f xp) {
        v2f ar = brv, az = bzv, an = bnv;
        #pragma unroll
        for (int d = 0; d < 8; ++d) {
            ar = pk_fma(wr[d], hp[d], ar);
            az = pk_fma(wz[d], hp[d], az);
            an = pk_fma(wn[d], hp[d], an);
        }
        const v2f sr = pk_fma(xp, wirv, ar);        // scaled pre-act r (both slots)
        const v2f sz = pk_fma(xp, wizv, az);        // scaled pre-act z

        // 4 sigmoids, ONE rcp
        const float er0 = exp2_fast(sr.x), er1 = exp2_fast(sr.y);
        const float ez0 = exp2_fast(sz.x), ez1 = exp2_fast(sz.y);
        const float dr0 = 1.0f + er0, dr1 = 1.0f + er1;
        const float dz0 = 1.0f + ez0, dz1 = 1.0f + ez1;
        const float P0  = dr0 * dz0,  P1  = dr1 * dz1;
        const float rp  = rcp_fast(P0 * P1);
        const float rpA = rp * P1,    rpB = rp * P0;    // 1/P0, 1/P1
        const v2f r01 = { dz0 * rpA, dz1 * rpB };
        const v2f z01 = { dr0 * rpA, dr1 * rpB };

        // n = tanh(pre), 2 tanh share ONE rcp
        v2f pre = pk_fma(xp, winv, binv);
        pre = pk_fma(r01, an, pre);
        const float en0 = exp2_fast(pre.x), en1 = exp2_fast(pre.y);
        const float Dn0 = 1.0f + en0, Dn1 = 1.0f + en1;
        const float rpn = rcp_fast(Dn0 * Dn1);
        const v2f rn  = { rpn * Dn1, rpn * Dn0 };
        const v2f n01 = pk_fma(C_NEG2, rn, C_ONE);  // tanh

        const v2f hm = hp[0] - n01;
        hp[0] = pk_fma(z01, hm, n01);               // h' = n + z*(h-n)

        // allgather (14 DPP): direct d=1,2,3,7 from h; d=6,5,4 from d=7
        const float g0 = hp[0].x, g1 = hp[0].y;
        float a7x = dppf<HALF_MIRROR>(g0);
        float a7y = dppf<HALF_MIRROR>(g1);
        hp[1] = v2f{ dppf<QP_XOR1>(g0), dppf<QP_XOR1>(g1) };
        hp[2] = v2f{ dppf<QP_XOR2>(g0), dppf<QP_XOR2>(g1) };
        hp[3] = v2f{ dppf<QP_XOR3>(g0), dppf<QP_XOR3>(g1) };
        hp[7] = v2f{ a7x, a7y };
        hp[6] = v2f{ dppf<QP_XOR1>(a7x), dppf<QP_XOR1>(a7y) };
        hp[5] = v2f{ dppf<QP_XOR2>(a7x), dppf<QP_XOR2>(a7y) };
        hp[4] = v2f{ dppf<QP_XOR3>(a7x), dppf<QP_XOR3>(a7y) };
    };

    // ---------------- encoder: 512 steps, prefetch distance 2, tail peeled ----------------
    const float* xp = x + e0;
    v2f xa0 = { xp[0],     xp[32] };
    v2f xa1 = { xp[BATCH], xp[BATCH + 32] };
    xp += 2 * (size_t)BATCH;
    #pragma unroll 2
    for (int t = 0; t < T_IN - 2; ++t) {
        const v2f xa2 = { xp[0], xp[32] };
        xp += BATCH;
        cell2(xa0);
        xa0 = xa1; xa1 = xa2;
    }
    cell2(xa0);      // t = 510
    cell2(xa1);      // t = 511; xa1 == x[511] == decoder first input

    // ---------------- decoder: 128 steps ----------------
    load_w(dWih, dWhh, dBih, dBhh);
    v2f fw[8];
    #pragma unroll
    for (int d = 0; d < 8; ++d) fw[d] = dup(fcW[u ^ d]);
    const v2f fbv = dup(fcB[0]);

    v2f inp = xa1;
    float* outp = out + e0;
    #pragma unroll 1
    for (int t = 0; t < T_OUT; ++t) {
        cell2(inp);
        v2f ay = fbv;
        #pragma unroll
        for (int d = 0; d < 8; ++d) ay = pk_fma(fw[d], hp[d], ay);
        if (u == 0) {
            outp[t * BATCH]      = ay.x;
            outp[t * BATCH + 32] = ay.y;
        }
        inp = ay;
    }
}

extern "C" void kernel_launch(void* const* d_in, const int* in_sizes, int n_in,
                              void* d_out, int out_size, void* d_ws, size_t ws_size,
                              hipStream_t stream) {
    const float* x    = (const float*)d_in[0];
    const float* eWih = (const float*)d_in[1];
    const float* eWhh = (const float*)d_in[2];
    const float* eBih = (const float*)d_in[3];
    const float* eBhh = (const float*)d_in[4];
    const float* dWih = (const float*)d_in[5];
    const float* dWhh = (const float*)d_in[6];
    const float* dBih = (const float*)d_in[7];
    const float* dBhh = (const float*)d_in[8];
    const float* fcW  = (const float*)d_in[9];
    const float* fcB  = (const float*)d_in[10];
    float* out = (float*)d_out;

    dim3 grid(BATCH / 64);   // 1024 blocks; 2 elements per thread
    dim3 block(256);
    gru_seq2seq<<<grid, block, 0, stream>>>(x, eWih, eWhh, eBih, eBhh,
                                            dWih, dWhh, dBih, dBhh,
                                            fcW, fcB, out);
}